// Round 6
// baseline (12452.914 us; speedup 1.0000x reference)
//
#include <hip/hip_runtime.h>

// DKVMN fused forward, round 6.
// grid = B = 256 blocks x 512 threads (8 waves, waves_per_eu(2) -> VGPR cap 256).
// R5 lessons: (1) pinning e/a (64 regs) spilled at VGPR=128 (+9 GB scratch);
// (2) ug in low lane bits made gate v-reads 4-way bank-conflicted (2e8 cycles).
// R6: no pins. Stream processes 8-row chunks, so the loop-invariant e/a LDS
// reads amortize to 2 b128 per 8 rows per u (4x less LDS than R4), w read as
// 2 broadcast b128 per (u,chunk). One 8-row prefetch buffer keeps ~4KB/wave
// in flight. Gates: wave-uniform ug (broadcast v-reads, 0 conflicts), 2 output
// dims per thread (v-read count halved vs R4), SU=16 -> 16 accum regs.
// State fp16 in d_ws (64 MB), U=8 steps/pass, 64 passes -> 8.2 GB traffic.
// LDS: wv 16K + e 16K + a 16K + q 2K + r 8K + h1 2K = 60 KB.

#define B_ 256
#define T_ 512
#define N_ 512
#define DK_ 64
#define DV_ 256
#define S_ 64
#define U_ 8
#define SU_ 16
#define NTB 512
#define NSUPER (T_ / SU_)   // 32
#define PPS (SU_ / U_)      // 2

typedef _Float16 h16;
typedef __attribute__((ext_vector_type(4))) _Float16 half4;

__device__ __forceinline__ float dot4(float4 a, float4 b) {
  return a.x * b.x + a.y * b.y + a.z * b.z + a.w * b.w;
}
__device__ __forceinline__ float4 h2f(half4 h) {
  return make_float4((float)h.x, (float)h.y, (float)h.z, (float)h.w);
}
__device__ __forceinline__ half4 f2h(float4 f) {
  half4 h;
  h.x = (h16)f.x; h.y = (h16)f.y; h.z = (h16)f.z; h.w = (h16)f.w;
  return h;
}

__global__ void __attribute__((amdgpu_flat_work_group_size(NTB, NTB),
                               amdgpu_waves_per_eu(2)))
dkvmn_fused(
    const int* __restrict__ concepts, const int* __restrict__ interactions,
    const float* __restrict__ Kmem, const float* __restrict__ Vmem,
    const float* __restrict__ cemb, const float* __restrict__ iemb,
    const float* __restrict__ We, const float* __restrict__ be,
    const float* __restrict__ Wa, const float* __restrict__ ba,
    const float* __restrict__ W1, const float* __restrict__ b1,
    const float* __restrict__ W2, const float* __restrict__ b2,
    const float* __restrict__ W3, const float* __restrict__ b3,
    float* __restrict__ out, h16* __restrict__ state) {
  __shared__ float s_wv[SU_ * DV_];  // 16 KB: v[16][256] gate phase; w[8][512] passes
  __shared__ float s_e[SU_][DV_];    // 16 KB
  __shared__ float s_a[SU_][DV_];    // 16 KB
  __shared__ float s_q[U_][DK_];     // 2 KB
  __shared__ float s_r[U_][DV_];     // 8 KB
  __shared__ float s_h1[U_][S_];     // 2 KB
  float (*s_w)[N_] = (float(*)[N_])s_wv;

  const int tid = threadIdx.x;
  const int b = blockIdx.x;
  const int lane = tid & 63;
  const int wid = tid >> 6;  // 8 waves
  half4* stb = (half4*)state + (size_t)b * (N_ * DV_ / 4);

  // ---- init fp16 state from Vmem ----
  {
    const float4* vm4 = (const float4*)Vmem;
    for (int idx = tid; idx < N_ * DV_ / 4; idx += NTB) stb[idx] = f2h(vm4[idx]);
  }

  for (int sp = 0; sp < NSUPER; ++sp) {
    const int s0 = sp * SU_;
    __syncthreads();  // G0: prev super-pass readers of s_wv/s_e/s_a done

    // ---- stage v: 16 steps of interaction embeds ----
    {
      const float4* iemb4 = (const float4*)iemb;
      for (int idx = tid; idx < SU_ * (DV_ / 4); idx += NTB) {
        const int u16 = idx >> 6, f = idx & 63;
        const int iv = interactions[b * T_ + s0 + u16];
        *(float4*)&s_wv[u16 * DV_ + f * 4] =
            iv ? iemb4[(size_t)iv * (DV_ / 4) + f] : make_float4(0.f, 0.f, 0.f, 0.f);
      }
    }
    __syncthreads();  // G1: v staged

    // ---- gates for 16 steps: thread owns 2 d's (d, d+128) x 4 u's ----
    // ug = tid>>7 (wave-uniform): v-reads are same-address broadcasts (0 conflict).
    {
      const int dp = tid & 127, ug = tid >> 7;  // ug in 0..3
      const int d0 = dp, d1 = dp + 128;
      float accE0[4], accE1[4], accA0[4], accA1[4];
#pragma unroll
      for (int j = 0; j < 4; ++j) { accE0[j] = accE1[j] = accA0[j] = accA1[j] = 0.f; }
      const float4* We4 = (const float4*)We;
      const float4* Wa4 = (const float4*)Wa;
      for (int kk = 0; kk < DV_ / 4; ++kk) {
        const float4 we0 = We4[(size_t)d0 * 64 + kk], we1 = We4[(size_t)d1 * 64 + kk];
        const float4 wa0 = Wa4[(size_t)d0 * 64 + kk], wa1 = Wa4[(size_t)d1 * 64 + kk];
#pragma unroll
        for (int j = 0; j < 4; ++j) {
          const float4 v4 = *(const float4*)&s_wv[(ug * 4 + j) * DV_ + kk * 4];
          accE0[j] += dot4(we0, v4);
          accE1[j] += dot4(we1, v4);
          accA0[j] += dot4(wa0, v4);
          accA1[j] += dot4(wa1, v4);
        }
      }
      const float be0 = be[d0], be1 = be[d1], ba0 = ba[d0], ba1 = ba[d1];
#pragma unroll
      for (int j = 0; j < 4; ++j) {
        const int u = ug * 4 + j;
        s_e[u][d0] = 1.f / (1.f + expf(-(accE0[j] + be0)));
        s_e[u][d1] = 1.f / (1.f + expf(-(accE1[j] + be1)));
        s_a[u][d0] = tanhf(accA0[j] + ba0);
        s_a[u][d1] = tanhf(accA1[j] + ba1);
      }
    }
    // gate writes ordered before stream reads by barriers A..D of pass 0.

    for (int p = 0; p < PPS; ++p) {
      const int t0 = s0 + p * U_;
      const int ub = p * U_;
      __syncthreads();  // A: prev MLP done with s_q/s_r/s_h1; gates done (p==0)

      // ---- stage q: 512 threads = 8u x 64 ----
      {
        const int c = concepts[b * T_ + t0 + wid];
        s_q[wid][lane] = c ? cemb[c * DK_ + lane] : 0.f;
      }
      __syncthreads();  // B

      // ---- logits: n = tid, 8 u's per thread ----
      {
        const int n = tid;
        const float4* kr = (const float4*)(Kmem + n * DK_);
        float acc[8];
#pragma unroll
        for (int j = 0; j < 8; ++j) acc[j] = 0.f;
#pragma unroll
        for (int kk = 0; kk < DK_ / 4; ++kk) {
          const float4 k4 = kr[kk];
#pragma unroll
          for (int j = 0; j < 8; ++j)
            acc[j] += dot4(k4, *(const float4*)&s_q[j][kk * 4]);
        }
#pragma unroll
        for (int j = 0; j < 8; ++j) s_w[j][n] = acc[j];
      }
      __syncthreads();  // C

      // ---- softmax (wave wid owns u=wid) + zero s_r ----
      {
        const int u = wid;
        *(float4*)&s_r[u][lane * 4] = make_float4(0.f, 0.f, 0.f, 0.f);
        float lg[8], mx = -1e30f;
#pragma unroll
        for (int k = 0; k < 8; ++k) {
          lg[k] = s_w[u][lane + 64 * k];
          mx = fmaxf(mx, lg[k]);
        }
        for (int off = 32; off > 0; off >>= 1) mx = fmaxf(mx, __shfl_xor(mx, off, 64));
        float sum = 0.f;
#pragma unroll
        for (int k = 0; k < 8; ++k) {
          lg[k] = expf(lg[k] - mx);
          sum += lg[k];
        }
        for (int off = 32; off > 0; off >>= 1) sum += __shfl_xor(sum, off, 64);
        const float inv = 1.f / sum;
#pragma unroll
        for (int k = 0; k < 8; ++k) s_w[u][lane + 64 * k] = lg[k] * inv;
      }
      __syncthreads();  // D

      // ---- stream: wave owns 64 rows; 8-row chunks, 1-chunk prefetch ----
      {
        const int d4 = lane;
        const int n0 = wid * 64;
        float4 racc[U_];
#pragma unroll
        for (int u = 0; u < U_; ++u) racc[u] = make_float4(0.f, 0.f, 0.f, 0.f);
        half4 buf[8];
#pragma unroll
        for (int r = 0; r < 8; ++r) buf[r] = stb[(n0 + r) * 64 + d4];
        for (int c0 = 0; c0 < 64; c0 += 8) {
          float4 m[8];
#pragma unroll
          for (int r = 0; r < 8; ++r) m[r] = h2f(buf[r]);
          const bool more = (c0 + 8) < 64;
          if (more) {
#pragma unroll
            for (int r = 0; r < 8; ++r) buf[r] = stb[(n0 + c0 + 8 + r) * 64 + d4];
          }
#pragma unroll
          for (int u = 0; u < U_; ++u) {
            const float4 eu = *(const float4*)&s_e[ub + u][d4 * 4];
            const float4 au = *(const float4*)&s_a[ub + u][d4 * 4];
            const float4 wA = *(const float4*)&s_w[u][n0 + c0];
            const float4 wB = *(const float4*)&s_w[u][n0 + c0 + 4];
#pragma unroll
            for (int r = 0; r < 8; ++r) {
              const float w = (r == 0) ? wA.x : (r == 1) ? wA.y : (r == 2) ? wA.z
                            : (r == 3) ? wA.w : (r == 4) ? wB.x : (r == 5) ? wB.y
                            : (r == 6) ? wB.z : wB.w;
              racc[u].x = fmaf(w, m[r].x, racc[u].x);
              racc[u].y = fmaf(w, m[r].y, racc[u].y);
              racc[u].z = fmaf(w, m[r].z, racc[u].z);
              racc[u].w = fmaf(w, m[r].w, racc[u].w);
              m[r].x = fmaf(-w, fmaf(eu.x, m[r].x, -au.x), m[r].x);
              m[r].y = fmaf(-w, fmaf(eu.y, m[r].y, -au.y), m[r].y);
              m[r].z = fmaf(-w, fmaf(eu.z, m[r].z, -au.z), m[r].z);
              m[r].w = fmaf(-w, fmaf(eu.w, m[r].w, -au.w), m[r].w);
            }
          }
#pragma unroll
          for (int r = 0; r < 8; ++r) stb[(n0 + c0 + r) * 64 + d4] = f2h(m[r]);
        }
#pragma unroll
        for (int u = 0; u < U_; ++u) {
          atomicAdd(&s_r[u][d4 * 4 + 0], racc[u].x);
          atomicAdd(&s_r[u][d4 * 4 + 1], racc[u].y);
          atomicAdd(&s_r[u][d4 * 4 + 2], racc[u].z);
          atomicAdd(&s_r[u][d4 * 4 + 3], racc[u].w);
        }
      }
      __syncthreads();  // E

      // ---- MLP layer 1 (8 waves, u=wid) ----
      {
        const int u = wid;
        float acc = b1[lane];
        const float4* w1r = (const float4*)(W1 + lane * (DV_ + DK_));
#pragma unroll
        for (int kk = 0; kk < DV_ / 4; ++kk)
          acc += dot4(w1r[kk], *(const float4*)&s_r[u][kk * 4]);
#pragma unroll
        for (int kk = 0; kk < DK_ / 4; ++kk)
          acc += dot4(w1r[DV_ / 4 + kk], *(const float4*)&s_q[u][kk * 4]);
        s_h1[u][lane] = fmaxf(acc, 0.f);
      }
      __syncthreads();  // F

      // ---- MLP layer 2 + head ----
      {
        const int u = wid;
        float acc = b2[lane];
        const float4* w2r = (const float4*)(W2 + lane * S_);
#pragma unroll
        for (int kk = 0; kk < S_ / 4; ++kk)
          acc += dot4(w2r[kk], *(const float4*)&s_h1[u][kk * 4]);
        float pp = fmaxf(acc, 0.f) * W3[lane];
        for (int off = 32; off > 0; off >>= 1) pp += __shfl_xor(pp, off, 64);
        if (lane == 0)
          out[(size_t)b * T_ + t0 + u] = 1.f / (1.f + expf(-(pp + b3[0])));
      }
    }  // pass
  }    // super-pass
}

extern "C" void kernel_launch(void* const* d_in, const int* in_sizes, int n_in,
                              void* d_out, int out_size, void* d_ws, size_t ws_size,
                              hipStream_t stream) {
  const int* concepts = (const int*)d_in[0];
  const int* interactions = (const int*)d_in[1];
  const float* Kmem = (const float*)d_in[2];
  const float* Vmem = (const float*)d_in[3];
  const float* cemb = (const float*)d_in[4];
  const float* iemb = (const float*)d_in[5];
  const float* We = (const float*)d_in[6];
  const float* be = (const float*)d_in[7];
  const float* Wa = (const float*)d_in[8];
  const float* ba = (const float*)d_in[9];
  const float* W1 = (const float*)d_in[10];
  const float* b1 = (const float*)d_in[11];
  const float* W2 = (const float*)d_in[12];
  const float* b2 = (const float*)d_in[13];
  const float* W3 = (const float*)d_in[14];
  const float* b3 = (const float*)d_in[15];
  float* out = (float*)d_out;
  h16* state = (h16*)d_ws;  // B*N*DV fp16 = 64 MiB

  dkvmn_fused<<<dim3(B_), dim3(NTB), 0, stream>>>(
      concepts, interactions, Kmem, Vmem, cemb, iemb, We, be, Wa, ba,
      W1, b1, W2, b2, W3, b3, out, state);
}

// Round 7
// 8321.191 us; speedup vs baseline: 1.4965x; 1.4965x over previous
//
#include <hip/hip_runtime.h>

// DKVMN forward, round 7 — decoupled 4-kernel pipeline.
// w,e,a depend only on inputs; the M-recurrence is independent per row n;
// r = sum_n w_n M_n feeds only the MLP. So:
//   kW: softmax weights w (fp16, ws) for all (b,t); zeros r accumulator.
//   kG: erase/add gates e,a (fp16, ws) for all (b,t).
//   kS: 1024 blocks x 512 thr; each wave holds 16 rows x float4 of M in 64
//       VGPRs for ALL 512 timesteps (zero global state traffic). Partial r
//       via conflict-free LDS planes + global atomicAdd.
//   kM: MLP for all 131072 (b,t) -> preds.
// ws: w 128MB + e 64 + a 64 + r 128 = 384 MiB. Fallback: R4 kernel (64 MB).

#define B_ 256
#define T_ 512
#define N_ 512
#define DK_ 64
#define DV_ 256
#define S_ 64
#define NP_ (B_ * T_)

typedef _Float16 h16;
typedef __attribute__((ext_vector_type(4))) _Float16 half4;

__device__ __forceinline__ float dot4(float4 a, float4 b) {
  return a.x * b.x + a.y * b.y + a.z * b.z + a.w * b.w;
}
__device__ __forceinline__ float4 h2f(half4 h) {
  return make_float4((float)h.x, (float)h.y, (float)h.z, (float)h.w);
}
__device__ __forceinline__ half4 f2h(float4 f) {
  half4 h;
  h.x = (h16)f.x; h.y = (h16)f.y; h.z = (h16)f.z; h.w = (h16)f.w;
  return h;
}

// ================= kernel W: logits + softmax -> w fp16; zero r ============
#define WP_ 32
__global__ __launch_bounds__(512) void kW(const int* __restrict__ concepts,
                                          const float* __restrict__ Kmem,
                                          const float* __restrict__ cemb,
                                          h16* __restrict__ w_h,
                                          float* __restrict__ r_zero) {
  __shared__ int s_c[WP_];
  __shared__ float s_q[WP_ * DK_];  // 8 KB
  __shared__ float s_l[WP_ * N_];   // 64 KB
  const int tid = threadIdx.x, g = blockIdx.x;
  // zero r: grid(4096)*512 threads * 4 float4 = 8,388,608 float4 = all of r
  {
    float4* r4 = (float4*)r_zero;
    const int base = g * 512 + tid;
    const float4 z = make_float4(0.f, 0.f, 0.f, 0.f);
#pragma unroll
    for (int i = 0; i < 4; ++i) r4[base + i * 2097152] = z;
  }
  if (tid < WP_) s_c[tid] = concepts[g * WP_ + tid];
  __syncthreads();
  for (int idx = tid; idx < WP_ * DK_; idx += 512) {
    const int p = idx >> 6, k = idx & 63, c = s_c[p];
    s_q[idx] = c ? cemb[c * DK_ + k] : 0.f;
  }
  __syncthreads();
  {
    const int n = tid;  // 512 = N
    const float4* kr = (const float4*)(Kmem + n * DK_);
    float acc[WP_];
#pragma unroll
    for (int p = 0; p < WP_; ++p) acc[p] = 0.f;
#pragma unroll
    for (int kk = 0; kk < DK_ / 4; ++kk) {
      const float4 k4 = kr[kk];
#pragma unroll
      for (int p = 0; p < WP_; ++p)
        acc[p] += dot4(k4, *(const float4*)&s_q[p * DK_ + kk * 4]);
    }
#pragma unroll
    for (int p = 0; p < WP_; ++p) s_l[p * N_ + n] = acc[p];
  }
  __syncthreads();
  const int lane = tid & 63, wid = tid >> 6;
#pragma unroll
  for (int pi = 0; pi < 4; ++pi) {
    const int p = wid * 4 + pi;
    float lg[8], mx = -1e30f;
#pragma unroll
    for (int k = 0; k < 8; ++k) {
      lg[k] = s_l[p * N_ + lane + 64 * k];
      mx = fmaxf(mx, lg[k]);
    }
    for (int off = 32; off > 0; off >>= 1) mx = fmaxf(mx, __shfl_xor(mx, off, 64));
    float sum = 0.f;
#pragma unroll
    for (int k = 0; k < 8; ++k) {
      lg[k] = expf(lg[k] - mx);
      sum += lg[k];
    }
    for (int off = 32; off > 0; off >>= 1) sum += __shfl_xor(sum, off, 64);
    const float inv = 1.f / sum;
    h16* wp = w_h + (size_t)(g * WP_ + p) * N_;
#pragma unroll
    for (int k = 0; k < 8; ++k) wp[lane + 64 * k] = (h16)(lg[k] * inv);
  }
}

// ================= kernel G: gates -> e,a fp16 =============================
#define GP_ 32
__global__ __launch_bounds__(512) void kG(const int* __restrict__ inter,
                                          const float* __restrict__ iemb,
                                          const float* __restrict__ We,
                                          const float* __restrict__ be,
                                          const float* __restrict__ Wa,
                                          const float* __restrict__ ba,
                                          h16* __restrict__ e_h,
                                          h16* __restrict__ a_h) {
  __shared__ int s_i[GP_];
  __shared__ float s_v[GP_ * DV_];  // 32 KB
  const int tid = threadIdx.x, g = blockIdx.x;
  if (tid < GP_) s_i[tid] = inter[g * GP_ + tid];
  __syncthreads();
  {
    const float4* iemb4 = (const float4*)iemb;
    const float4 z = make_float4(0.f, 0.f, 0.f, 0.f);
    for (int idx = tid; idx < GP_ * (DV_ / 4); idx += 512) {
      const int p = idx >> 6, c4 = idx & 63, iv = s_i[p];
      ((float4*)s_v)[idx] = iv ? iemb4[(size_t)iv * 64 + c4] : z;
    }
  }
  __syncthreads();
  const int o = tid, gate = o >> 8, d = o & 255;  // gate wave-uniform
  const float4* wr = (const float4*)((gate ? Wa : We) + d * DV_);
  const float bias = gate ? ba[d] : be[d];
  float acc[GP_];
#pragma unroll
  for (int p = 0; p < GP_; ++p) acc[p] = 0.f;
  for (int kk = 0; kk < DV_ / 4; ++kk) {
    const float4 w4 = wr[kk];
#pragma unroll
    for (int p = 0; p < GP_; ++p)
      acc[p] += dot4(w4, *(const float4*)&s_v[p * DV_ + kk * 4]);
  }
  h16* outp = gate ? a_h : e_h;
#pragma unroll
  for (int p = 0; p < GP_; ++p) {
    const float x = acc[p] + bias;
    const float y = gate ? tanhf(x) : 1.f / (1.f + expf(-x));
    outp[(size_t)(g * GP_ + p) * DV_ + d] = (h16)y;
  }
}

// ================= kernel S: in-register recurrence ========================
#define NCH_ 4    // row-chunks per batch
#define NC_ 128   // rows per chunk
#define TB_ 16    // timesteps per LDS tile
__global__ void __attribute__((amdgpu_flat_work_group_size(512, 512),
                               amdgpu_waves_per_eu(4)))
kS(const float* __restrict__ Vmem, const h16* __restrict__ w_h,
   const h16* __restrict__ e_h, const h16* __restrict__ a_h,
   float* __restrict__ r) {
  __shared__ float s_wt[TB_][NC_];      // 8 KB
  __shared__ float s_e[TB_][DV_];       // 16 KB
  __shared__ float s_a[TB_][DV_];       // 16 KB
  __shared__ float s_rt[TB_][4][64];    // 16 KB, component planes (bank-clean)
  const int tid = threadIdx.x, bx = blockIdx.x;
  const int b = bx >> 2, ch = bx & 3;
  const int lane = tid & 63, wv = tid >> 6;  // 8 waves x 16 rows = 128 rows
  const int nbase = ch * NC_ + wv * 16;
  // state: 16 rows x float4, in registers for the whole sequence
  float4 m[16];
  {
    const float4* vm4 = (const float4*)Vmem;
#pragma unroll
    for (int rr = 0; rr < 16; ++rr) m[rr] = vm4[(nbase + rr) * 64 + lane];
  }
  const h16* wb = w_h + (size_t)b * T_ * N_ + ch * NC_;
  const h16* eb = e_h + (size_t)b * T_ * DV_;
  const h16* ab = a_h + (size_t)b * T_ * DV_;
  float* rb = r + (size_t)b * T_ * DV_;

  for (int t0 = 0; t0 < T_; t0 += TB_) {
    // ---- stage w (fp16 -> fp32), e, a; zero r_tile ----
    {
      const int tl = tid >> 5, q = tid & 31;
      *(float4*)&s_wt[tl][q * 4] =
          h2f(*(const half4*)(wb + (size_t)(t0 + tl) * N_ + q * 4));
    }
#pragma unroll
    for (int i = 0; i < 2; ++i) {
      const int idx = tid + i * 512;  // 0..1023
      const int tl = idx >> 6, c4 = idx & 63;
      *(float4*)&s_e[tl][c4 * 4] = h2f(*(const half4*)(eb + (t0 + tl) * DV_ + c4 * 4));
      *(float4*)&s_a[tl][c4 * 4] = h2f(*(const half4*)(ab + (t0 + tl) * DV_ + c4 * 4));
      ((float4*)s_rt)[idx] = make_float4(0.f, 0.f, 0.f, 0.f);
    }
    __syncthreads();

    // ---- 16 timesteps over register-resident state ----
    for (int tl = 0; tl < TB_; ++tl) {
      float wr_[16];
      *(float4*)&wr_[0] = *(const float4*)&s_wt[tl][wv * 16];
      *(float4*)&wr_[4] = *(const float4*)&s_wt[tl][wv * 16 + 4];
      *(float4*)&wr_[8] = *(const float4*)&s_wt[tl][wv * 16 + 8];
      *(float4*)&wr_[12] = *(const float4*)&s_wt[tl][wv * 16 + 12];
      const float4 e4 = *(const float4*)&s_e[tl][lane * 4];
      const float4 a4 = *(const float4*)&s_a[tl][lane * 4];
      float4 racc = make_float4(0.f, 0.f, 0.f, 0.f);
#pragma unroll
      for (int rr = 0; rr < 16; ++rr) {
        const float w = wr_[rr];
        racc.x = fmaf(w, m[rr].x, racc.x);
        racc.y = fmaf(w, m[rr].y, racc.y);
        racc.z = fmaf(w, m[rr].z, racc.z);
        racc.w = fmaf(w, m[rr].w, racc.w);
        m[rr].x = fmaf(-w, fmaf(e4.x, m[rr].x, -a4.x), m[rr].x);
        m[rr].y = fmaf(-w, fmaf(e4.y, m[rr].y, -a4.y), m[rr].y);
        m[rr].z = fmaf(-w, fmaf(e4.z, m[rr].z, -a4.z), m[rr].z);
        m[rr].w = fmaf(-w, fmaf(e4.w, m[rr].w, -a4.w), m[rr].w);
      }
      atomicAdd(&s_rt[tl][0][lane], racc.x);
      atomicAdd(&s_rt[tl][1][lane], racc.y);
      atomicAdd(&s_rt[tl][2][lane], racc.z);
      atomicAdd(&s_rt[tl][3][lane], racc.w);
    }
    __syncthreads();

    // ---- drain partial r to global (4 chunk-blocks accumulate) ----
#pragma unroll
    for (int i = 0; i < 2; ++i) {
      const int idx = tid + i * 512;
      const int tl = idx >> 6, c4 = idx & 63;
      float* rp = rb + (size_t)(t0 + tl) * DV_ + c4 * 4;
      atomicAdd(rp + 0, s_rt[tl][0][c4]);
      atomicAdd(rp + 1, s_rt[tl][1][c4]);
      atomicAdd(rp + 2, s_rt[tl][2][c4]);
      atomicAdd(rp + 3, s_rt[tl][3][c4]);
    }
    __syncthreads();  // before next tile's zeroing
  }
}

// ================= kernel M: MLP head ======================================
#define MP_ 64
__global__ __launch_bounds__(512) void kM(const int* __restrict__ concepts,
                                          const float* __restrict__ cemb,
                                          const float* __restrict__ r,
                                          const float* __restrict__ W1,
                                          const float* __restrict__ b1,
                                          const float* __restrict__ W2,
                                          const float* __restrict__ b2,
                                          const float* __restrict__ W3,
                                          const float* __restrict__ b3,
                                          float* __restrict__ out) {
  __shared__ float s_f[MP_][DV_ + DK_];  // 80 KB
  __shared__ h16 s_W1[S_][324];          // 40.5 KB (pad: 4-way conflict max)
  __shared__ float s_h1[8][8][S_];       // 16 KB
  __shared__ int s_c[MP_];
  const int tid = threadIdx.x, g = blockIdx.x;
  const int lane = tid & 63, wv = tid >> 6;
  if (tid < MP_) s_c[tid] = concepts[g * MP_ + tid];
  for (int idx = tid; idx < S_ * 320; idx += 512) {
    const int j = idx / 320, k = idx % 320;
    s_W1[j][k] = (h16)W1[j * 320 + k];
  }
  __syncthreads();
  {
    const float4* r4 = (const float4*)r;
#pragma unroll
    for (int i = 0; i < 8; ++i) {
      const int idx = tid + i * 512, p = idx >> 6, c4 = idx & 63;
      *(float4*)&s_f[p][c4 * 4] = r4[(size_t)(g * MP_ + p) * 64 + c4];
    }
    const float4* ce4 = (const float4*)cemb;
    const float4 z = make_float4(0.f, 0.f, 0.f, 0.f);
#pragma unroll
    for (int i = 0; i < 2; ++i) {
      const int idx = tid + i * 512, p = idx >> 4, k4 = idx & 15;
      const int c = s_c[p];
      *(float4*)&s_f[p][DV_ + k4 * 4] = c ? ce4[c * 16 + k4] : z;
    }
  }
  __syncthreads();
  // layer 1: lane = neuron, wave handles 8 pairs
  const int j = lane;
  float acc[8];
  {
    const float b1j = b1[j];
#pragma unroll
    for (int p = 0; p < 8; ++p) acc[p] = b1j;
  }
  for (int k4 = 0; k4 < 80; ++k4) {
    const float4 w4 = h2f(*(const half4*)&s_W1[j][k4 * 4]);
#pragma unroll
    for (int p = 0; p < 8; ++p)
      acc[p] += dot4(w4, *(const float4*)&s_f[wv * 8 + p][k4 * 4]);
  }
#pragma unroll
  for (int p = 0; p < 8; ++p) s_h1[wv][p][j] = fmaxf(acc[p], 0.f);
  __syncthreads();
  // layer 2 + head
  {
    const float b2j = b2[j];
#pragma unroll
    for (int p = 0; p < 8; ++p) acc[p] = b2j;
  }
  const float4* w2r = (const float4*)(W2 + j * S_);
#pragma unroll
  for (int k4 = 0; k4 < S_ / 4; ++k4) {
    const float4 w4 = w2r[k4];
#pragma unroll
    for (int p = 0; p < 8; ++p)
      acc[p] += dot4(w4, *(const float4*)&s_h1[wv][p][k4 * 4]);
  }
  const float w3j = W3[j], b3v = b3[0];
#pragma unroll
  for (int p = 0; p < 8; ++p) {
    float pp = fmaxf(acc[p], 0.f) * w3j;
    for (int off = 32; off > 0; off >>= 1) pp += __shfl_xor(pp, off, 64);
    if (lane == 0)
      out[g * MP_ + wv * 8 + p] = 1.f / (1.f + expf(-(pp + b3v)));
  }
}

// ================= fallback: R4 fused kernel (needs 64 MB ws) ==============
#define FBU 8
#define FBSU 32
#define FBNT 1024
#define FBNS (T_ / FBSU)
#define FBPP (FBSU / FBU)
__global__ void __attribute__((amdgpu_flat_work_group_size(FBNT, FBNT),
                               amdgpu_waves_per_eu(4, 4)))
dkvmn_fb(const int* __restrict__ concepts, const int* __restrict__ interactions,
         const float* __restrict__ Kmem, const float* __restrict__ Vmem,
         const float* __restrict__ cemb, const float* __restrict__ iemb,
         const float* __restrict__ We, const float* __restrict__ be,
         const float* __restrict__ Wa, const float* __restrict__ ba,
         const float* __restrict__ W1, const float* __restrict__ b1,
         const float* __restrict__ W2, const float* __restrict__ b2,
         const float* __restrict__ W3, const float* __restrict__ b3,
         float* __restrict__ out, h16* __restrict__ state) {
  __shared__ float s_wv[FBSU * DV_];
  __shared__ float s_e[FBSU][DV_];
  __shared__ float s_a[FBSU][DV_];
  __shared__ float s_q[FBU][DK_];
  __shared__ float s_r[FBU][DV_];
  __shared__ float s_h1[FBU][S_];
  float (*s_w)[N_] = (float(*)[N_])s_wv;
  const int tid = threadIdx.x;
  const int b = blockIdx.x;
  const int lane = tid & 63;
  const int wid = tid >> 6;
  half4* stb = (half4*)state + (size_t)b * (N_ * DV_ / 4);
  {
    const float4* vm4 = (const float4*)Vmem;
    for (int idx = tid; idx < N_ * DV_ / 4; idx += FBNT) stb[idx] = f2h(vm4[idx]);
  }
  for (int sp = 0; sp < FBNS; ++sp) {
    const int s0 = sp * FBSU;
    __syncthreads();
    {
      const float4* iemb4 = (const float4*)iemb;
      for (int idx = tid; idx < FBSU * (DV_ / 4); idx += FBNT) {
        const int u32 = idx >> 6, f = idx & 63;
        const int iv = interactions[b * T_ + s0 + u32];
        *(float4*)&s_wv[u32 * DV_ + f * 4] =
            iv ? iemb4[(size_t)iv * (DV_ / 4) + f] : make_float4(0.f, 0.f, 0.f, 0.f);
      }
    }
    __syncthreads();
    {
      const int d = tid & (DV_ - 1), ug = tid >> 8;
      float accE[8], accA[8];
#pragma unroll
      for (int jj = 0; jj < 8; ++jj) { accE[jj] = 0.f; accA[jj] = 0.f; }
      const float4* We4 = (const float4*)(We + d * DV_);
      const float4* Wa4 = (const float4*)(Wa + d * DV_);
      for (int kk = 0; kk < DV_ / 4; ++kk) {
        const float4 we = We4[kk], wa = Wa4[kk];
#pragma unroll
        for (int jj = 0; jj < 8; ++jj) {
          const float4 v4 = *(const float4*)&s_wv[(ug * 8 + jj) * DV_ + kk * 4];
          accE[jj] += dot4(we, v4);
          accA[jj] += dot4(wa, v4);
        }
      }
      const float bed = be[d], bad = ba[d];
#pragma unroll
      for (int jj = 0; jj < 8; ++jj) {
        s_e[ug * 8 + jj][d] = 1.f / (1.f + expf(-(accE[jj] + bed)));
        s_a[ug * 8 + jj][d] = tanhf(accA[jj] + bad);
      }
    }
    for (int p = 0; p < FBPP; ++p) {
      const int t0 = s0 + p * FBU;
      const int ub = p * FBU;
      __syncthreads();
      if (tid < FBU * DK_) {
        const int u = tid >> 6, l = tid & 63;
        const int c = concepts[b * T_ + t0 + u];
        s_q[u][l] = c ? cemb[c * DK_ + l] : 0.f;
      }
      __syncthreads();
      {
        const int n = tid & (N_ - 1), ug = tid >> 9;
        const float4* kr = (const float4*)(Kmem + n * DK_);
        float acc[4] = {0.f, 0.f, 0.f, 0.f};
#pragma unroll
        for (int kk = 0; kk < DK_ / 4; ++kk) {
          const float4 k4 = kr[kk];
#pragma unroll
          for (int jj = 0; jj < 4; ++jj)
            acc[jj] += dot4(k4, *(const float4*)&s_q[ug * 4 + jj][kk * 4]);
        }
#pragma unroll
        for (int jj = 0; jj < 4; ++jj) s_w[ug * 4 + jj][n] = acc[jj];
      }
      __syncthreads();
      if (wid < FBU) {
        const int u = wid;
        float lg[8], mx = -1e30f;
#pragma unroll
        for (int k = 0; k < 8; ++k) {
          lg[k] = s_w[u][lane + 64 * k];
          mx = fmaxf(mx, lg[k]);
        }
        for (int off = 32; off > 0; off >>= 1) mx = fmaxf(mx, __shfl_xor(mx, off, 64));
        float sum = 0.f;
#pragma unroll
        for (int k = 0; k < 8; ++k) {
          lg[k] = expf(lg[k] - mx);
          sum += lg[k];
        }
        for (int off = 32; off > 0; off >>= 1) sum += __shfl_xor(sum, off, 64);
        const float inv = 1.f / sum;
#pragma unroll
        for (int k = 0; k < 8; ++k) s_w[u][lane + 64 * k] = lg[k] * inv;
      } else {
        *(float4*)&s_r[wid - 8][lane * 4] = make_float4(0.f, 0.f, 0.f, 0.f);
      }
      __syncthreads();
      {
        const int d4 = lane;
        float4 racc[FBU];
#pragma unroll
        for (int u = 0; u < FBU; ++u) racc[u] = make_float4(0.f, 0.f, 0.f, 0.f);
        const int n0 = wid * 32;
        half4 cA = stb[(n0 + 0) * 64 + d4];
        half4 cB = stb[(n0 + 1) * 64 + d4];
        for (int c = 0; c < 32; c += 2) {
          half4 nxA, nxB;
          const bool more = (c + 2) < 32;
          if (more) {
            nxA = stb[(n0 + c + 2) * 64 + d4];
            nxB = stb[(n0 + c + 3) * 64 + d4];
          }
          float4 mA = h2f(cA), mB = h2f(cB);
          const int na = n0 + c, nb2 = na + 1;
#pragma unroll
          for (int u = 0; u < FBU; ++u) {
            const float w0 = s_w[u][na], w1 = s_w[u][nb2];
            const float4 eu = *(const float4*)&s_e[ub + u][d4 * 4];
            const float4 au = *(const float4*)&s_a[ub + u][d4 * 4];
            racc[u].x = fmaf(w0, mA.x, racc[u].x);
            racc[u].y = fmaf(w0, mA.y, racc[u].y);
            racc[u].z = fmaf(w0, mA.z, racc[u].z);
            racc[u].w = fmaf(w0, mA.w, racc[u].w);
            mA.x = fmaf(-w0, fmaf(eu.x, mA.x, -au.x), mA.x);
            mA.y = fmaf(-w0, fmaf(eu.y, mA.y, -au.y), mA.y);
            mA.z = fmaf(-w0, fmaf(eu.z, mA.z, -au.z), mA.z);
            mA.w = fmaf(-w0, fmaf(eu.w, mA.w, -au.w), mA.w);
            racc[u].x = fmaf(w1, mB.x, racc[u].x);
            racc[u].y = fmaf(w1, mB.y, racc[u].y);
            racc[u].z = fmaf(w1, mB.z, racc[u].z);
            racc[u].w = fmaf(w1, mB.w, racc[u].w);
            mB.x = fmaf(-w1, fmaf(eu.x, mB.x, -au.x), mB.x);
            mB.y = fmaf(-w1, fmaf(eu.y, mB.y, -au.y), mB.y);
            mB.z = fmaf(-w1, fmaf(eu.z, mB.z, -au.z), mB.z);
            mB.w = fmaf(-w1, fmaf(eu.w, mB.w, -au.w), mB.w);
          }
          stb[na * 64 + d4] = f2h(mA);
          stb[nb2 * 64 + d4] = f2h(mB);
          if (more) { cA = nxA; cB = nxB; }
        }
#pragma unroll
        for (int u = 0; u < FBU; ++u) {
          atomicAdd(&s_r[u][d4 * 4 + 0], racc[u].x);
          atomicAdd(&s_r[u][d4 * 4 + 1], racc[u].y);
          atomicAdd(&s_r[u][d4 * 4 + 2], racc[u].z);
          atomicAdd(&s_r[u][d4 * 4 + 3], racc[u].w);
        }
      }
      __syncthreads();
      if (tid < FBU * 64) {
        const int u = wid;
        float acc = b1[lane];
        const float4* w1r = (const float4*)(W1 + lane * (DV_ + DK_));
#pragma unroll
        for (int kk = 0; kk < DV_ / 4; ++kk)
          acc += dot4(w1r[kk], *(const float4*)&s_r[u][kk * 4]);
#pragma unroll
        for (int kk = 0; kk < DK_ / 4; ++kk)
          acc += dot4(w1r[DV_ / 4 + kk], *(const float4*)&s_q[u][kk * 4]);
        s_h1[u][lane] = fmaxf(acc, 0.f);
      }
      __syncthreads();
      if (tid < FBU * 64) {
        const int u = wid;
        float acc = b2[lane];
        const float4* w2r = (const float4*)(W2 + lane * S_);
#pragma unroll
        for (int kk = 0; kk < S_ / 4; ++kk)
          acc += dot4(w2r[kk], *(const float4*)&s_h1[u][kk * 4]);
        float pp = fmaxf(acc, 0.f) * W3[lane];
        for (int off = 32; off > 0; off >>= 1) pp += __shfl_xor(pp, off, 64);
        if (lane == 0)
          out[(size_t)b * T_ + t0 + u] = 1.f / (1.f + expf(-(pp + b3[0])));
      }
    }
  }
}

extern "C" void kernel_launch(void* const* d_in, const int* in_sizes, int n_in,
                              void* d_out, int out_size, void* d_ws, size_t ws_size,
                              hipStream_t stream) {
  const int* concepts = (const int*)d_in[0];
  const int* interactions = (const int*)d_in[1];
  const float* Kmem = (const float*)d_in[2];
  const float* Vmem = (const float*)d_in[3];
  const float* cemb = (const float*)d_in[4];
  const float* iemb = (const float*)d_in[5];
  const float* We = (const float*)d_in[6];
  const float* be = (const float*)d_in[7];
  const float* Wa = (const float*)d_in[8];
  const float* ba = (const float*)d_in[9];
  const float* W1 = (const float*)d_in[10];
  const float* b1 = (const float*)d_in[11];
  const float* W2 = (const float*)d_in[12];
  const float* b2 = (const float*)d_in[13];
  const float* W3 = (const float*)d_in[14];
  const float* b3 = (const float*)d_in[15];
  float* out = (float*)d_out;

  const size_t off_e = (size_t)NP_ * N_ * 2;            // 128 MiB
  const size_t off_a = off_e + (size_t)NP_ * DV_ * 2;   // +64 MiB
  const size_t off_r = off_a + (size_t)NP_ * DV_ * 2;   // +64 MiB
  const size_t need = off_r + (size_t)NP_ * DV_ * 4;    // +128 MiB = 384 MiB

  if (ws_size >= need) {
    h16* w_h = (h16*)d_ws;
    h16* e_h = (h16*)((char*)d_ws + off_e);
    h16* a_h = (h16*)((char*)d_ws + off_a);
    float* r = (float*)((char*)d_ws + off_r);
    kW<<<dim3(NP_ / WP_), dim3(512), 0, stream>>>(concepts, Kmem, cemb, w_h, r);
    kG<<<dim3(NP_ / GP_), dim3(512), 0, stream>>>(interactions, iemb, We, be, Wa, ba, e_h, a_h);
    kS<<<dim3(B_ * NCH_), dim3(512), 0, stream>>>(Vmem, w_h, e_h, a_h, r);
    kM<<<dim3(NP_ / MP_), dim3(512), 0, stream>>>(concepts, cemb, r, W1, b1, W2, b2, W3, b3, out);
  } else {
    dkvmn_fb<<<dim3(B_), dim3(FBNT), 0, stream>>>(
        concepts, interactions, Kmem, Vmem, cemb, iemb, We, be, Wa, ba,
        W1, b1, W2, b2, W3, b3, out, (h16*)d_ws);
  }
}

// Round 8
// 6399.618 us; speedup vs baseline: 1.9459x; 1.3003x over previous
//
#include <hip/hip_runtime.h>

// DKVMN forward, round 8 — table-driven pipeline (fits 138 MiB < 256 MiB ws).
// Key insight: w = softmax(q_c·K^T) depends only on concept id c (513 values);
// e,a depend only on interaction id i (1025 values). Precompute tiny tables:
//   kW: wtab[513][512] fp32 (1 MiB)   kG: etab/atab[1025][256] fp32 (2.1 MiB)
// kS: 1024 blocks (b x 4 row-chunks) x 512 thr; each wave holds 16 rows x
//     float4 of M in 64 VGPRs for ALL 512 steps (zero state traffic; m is a
//     true register recurrence — cannot be rematerialized). Per 16-step tile:
//     stage w/e/a from hot tables -> LDS, recurrence, partial r via LDS
//     planes -> global fp32 atomicAdd (r zeroed by hipMemsetAsync).
// kM: MLP over all 131072 (b,t).

#define B_ 256
#define T_ 512
#define N_ 512
#define DK_ 64
#define DV_ 256
#define S_ 64
#define NP_ (B_ * T_)
#define NCID 513
#define NIID 1025
#define TB_ 16

typedef _Float16 h16;
typedef __attribute__((ext_vector_type(4))) _Float16 half4;

__device__ __forceinline__ float dot4(float4 a, float4 b) {
  return a.x * b.x + a.y * b.y + a.z * b.z + a.w * b.w;
}
__device__ __forceinline__ float4 h2f(half4 h) {
  return make_float4((float)h.x, (float)h.y, (float)h.z, (float)h.w);
}

// ============ kW: wtab[c][n] = softmax_n(q_c . K_n), 513 blocks ============
__global__ __launch_bounds__(512) void kW(const float* __restrict__ Kmem,
                                          const float* __restrict__ cemb,
                                          float* __restrict__ wtab) {
  __shared__ float s_q[DK_];
  __shared__ float s_red[16];
  const int tid = threadIdx.x, c = blockIdx.x;
  if (tid < DK_) s_q[tid] = c ? cemb[c * DK_ + tid] : 0.f;
  __syncthreads();
  const int n = tid;  // 512 threads = N
  const float4* kr = (const float4*)(Kmem + n * DK_);
  float acc = 0.f;
#pragma unroll
  for (int kk = 0; kk < DK_ / 4; ++kk) acc += dot4(kr[kk], *(const float4*)&s_q[kk * 4]);
  const int lane = tid & 63, wid = tid >> 6;
  float mx = acc;
  for (int off = 32; off; off >>= 1) mx = fmaxf(mx, __shfl_xor(mx, off, 64));
  if (lane == 0) s_red[wid] = mx;
  __syncthreads();
  float gmx = s_red[0];
#pragma unroll
  for (int i = 1; i < 8; ++i) gmx = fmaxf(gmx, s_red[i]);
  const float e = expf(acc - gmx);
  float sum = e;
  for (int off = 32; off; off >>= 1) sum += __shfl_xor(sum, off, 64);
  if (lane == 0) s_red[8 + wid] = sum;
  __syncthreads();
  float gs = 0.f;
#pragma unroll
  for (int i = 0; i < 8; ++i) gs += s_red[8 + i];
  wtab[c * N_ + n] = e / gs;
}

// ============ kG: etab/atab[id][d], 129 blocks x 8 ids =====================
__global__ __launch_bounds__(512) void kG(const float* __restrict__ iemb,
                                          const float* __restrict__ We,
                                          const float* __restrict__ be,
                                          const float* __restrict__ Wa,
                                          const float* __restrict__ ba,
                                          float* __restrict__ etab,
                                          float* __restrict__ atab) {
  __shared__ float s_v[8 * DV_];  // 8 KB
  const int tid = threadIdx.x, bi = blockIdx.x;
  {
    const int j = tid >> 6, c4 = tid & 63;
    const int id = bi * 8 + j;
    float4 v = make_float4(0.f, 0.f, 0.f, 0.f);
    if (id >= 1 && id < NIID) v = ((const float4*)iemb)[(size_t)id * 64 + c4];
    *(float4*)&s_v[j * DV_ + c4 * 4] = v;
  }
  __syncthreads();
  const int gate = tid >> 8, d = tid & 255;  // gate wave-uniform
  const float4* wr = (const float4*)((gate ? Wa : We) + d * DV_);
  float acc[8];
#pragma unroll
  for (int j = 0; j < 8; ++j) acc[j] = 0.f;
  for (int kk = 0; kk < DV_ / 4; ++kk) {
    const float4 w4 = wr[kk];
#pragma unroll
    for (int j = 0; j < 8; ++j) acc[j] += dot4(w4, *(const float4*)&s_v[j * DV_ + kk * 4]);
  }
  const float bias = gate ? ba[d] : be[d];
#pragma unroll
  for (int j = 0; j < 8; ++j) {
    const int id = bi * 8 + j;
    if (id < NIID) {
      if (gate) atab[(size_t)id * DV_ + d] = tanhf(acc[j] + bias);
      else      etab[(size_t)id * DV_ + d] = 1.f / (1.f + expf(-(acc[j] + bias)));
    }
  }
}

// ============ kS: in-register recurrence, 1024 blocks x 512 thr ============
__global__ void __attribute__((amdgpu_flat_work_group_size(512, 512),
                               amdgpu_waves_per_eu(4, 4)))
kS(const int* __restrict__ concepts, const int* __restrict__ inter,
   const float* __restrict__ Vmem, const float* __restrict__ wtab,
   const float* __restrict__ etab, const float* __restrict__ atab,
   float* __restrict__ r) {
  __shared__ float s_wt[TB_][128];    // 8 KB   w for this chunk's 128 rows
  __shared__ float s_e[TB_][DV_];     // 16 KB
  __shared__ float s_a[TB_][DV_];     // 16 KB
  __shared__ float s_rt[TB_][4][64];  // 16 KB  r partials, component planes
  const int tid = threadIdx.x, bx = blockIdx.x;
  const int b = bx >> 2, ch = bx & 3;
  const int lane = tid & 63, wv = tid >> 6;  // 8 waves x 16 rows = 128 rows
  float4 m[16];                              // 64 VGPRs of true state
  {
    const float4* vm4 = (const float4*)Vmem;
    const int nb = ch * 128 + wv * 16;
#pragma unroll
    for (int rr = 0; rr < 16; ++rr) m[rr] = vm4[(nb + rr) * 64 + lane];
  }
  const int* cb = concepts + b * T_;
  const int* ib = inter + b * T_;
  float* rb = r + (size_t)b * T_ * DV_;
  const float4* wtab4 = (const float4*)wtab;
  const float4* etab4 = (const float4*)etab;
  const float4* atab4 = (const float4*)atab;

  for (int t0 = 0; t0 < T_; t0 += TB_) {
    // ---- stage w/e/a tiles from hot tables; zero r planes ----
    {
      const int tl = tid >> 5, q = tid & 31;  // 512 = 16 x 32 float4
      const int c = cb[t0 + tl];
      ((float4*)s_wt)[tid] = wtab4[(size_t)c * 128 + ch * 32 + q];
    }
#pragma unroll
    for (int i = 0; i < 2; ++i) {
      const int idx = tid + i * 512;  // 0..1023
      const int tl = idx >> 6, c4 = idx & 63;
      const int iv = ib[t0 + tl];
      *(float4*)&s_e[tl][c4 * 4] = etab4[(size_t)iv * 64 + c4];
      *(float4*)&s_a[tl][c4 * 4] = atab4[(size_t)iv * 64 + c4];
      ((float4*)s_rt)[idx] = make_float4(0.f, 0.f, 0.f, 0.f);
    }
    __syncthreads();

    // ---- 16 timesteps over register-resident state ----
    for (int tl = 0; tl < TB_; ++tl) {
      float wr_[16];
      *(float4*)&wr_[0]  = *(const float4*)&s_wt[tl][wv * 16 + 0];
      *(float4*)&wr_[4]  = *(const float4*)&s_wt[tl][wv * 16 + 4];
      *(float4*)&wr_[8]  = *(const float4*)&s_wt[tl][wv * 16 + 8];
      *(float4*)&wr_[12] = *(const float4*)&s_wt[tl][wv * 16 + 12];
      const float4 e4 = *(const float4*)&s_e[tl][lane * 4];
      const float4 a4 = *(const float4*)&s_a[tl][lane * 4];
      float4 racc = make_float4(0.f, 0.f, 0.f, 0.f);
#pragma unroll
      for (int rr = 0; rr < 16; ++rr) {
        const float w = wr_[rr];
        racc.x = fmaf(w, m[rr].x, racc.x);
        racc.y = fmaf(w, m[rr].y, racc.y);
        racc.z = fmaf(w, m[rr].z, racc.z);
        racc.w = fmaf(w, m[rr].w, racc.w);
        m[rr].x = fmaf(-w, fmaf(e4.x, m[rr].x, -a4.x), m[rr].x);
        m[rr].y = fmaf(-w, fmaf(e4.y, m[rr].y, -a4.y), m[rr].y);
        m[rr].z = fmaf(-w, fmaf(e4.z, m[rr].z, -a4.z), m[rr].z);
        m[rr].w = fmaf(-w, fmaf(e4.w, m[rr].w, -a4.w), m[rr].w);
      }
      atomicAdd(&s_rt[tl][0][lane], racc.x);
      atomicAdd(&s_rt[tl][1][lane], racc.y);
      atomicAdd(&s_rt[tl][2][lane], racc.z);
      atomicAdd(&s_rt[tl][3][lane], racc.w);
    }
    __syncthreads();

    // ---- drain partial r to global (4 chunk-blocks accumulate) ----
#pragma unroll
    for (int i = 0; i < 2; ++i) {
      const int idx = tid + i * 512;
      const int tl = idx >> 6, l = idx & 63;
      float* rp = rb + (size_t)(t0 + tl) * DV_ + l * 4;
      atomicAdd(rp + 0, s_rt[tl][0][l]);
      atomicAdd(rp + 1, s_rt[tl][1][l]);
      atomicAdd(rp + 2, s_rt[tl][2][l]);
      atomicAdd(rp + 3, s_rt[tl][3][l]);
    }
    __syncthreads();
  }
}

// ============ kM: MLP head, 2048 blocks x 512 thr ==========================
#define MP_ 64
__global__ __launch_bounds__(512) void kM(const int* __restrict__ concepts,
                                          const float* __restrict__ cemb,
                                          const float* __restrict__ r,
                                          const float* __restrict__ W1,
                                          const float* __restrict__ b1,
                                          const float* __restrict__ W2,
                                          const float* __restrict__ b2,
                                          const float* __restrict__ W3,
                                          const float* __restrict__ b3,
                                          float* __restrict__ out) {
  __shared__ float s_f[MP_][DV_ + DK_];  // 80 KB
  __shared__ h16 s_W1[S_][324];          // 40.5 KB (padded)
  __shared__ float s_h1[8][8][S_];       // 16 KB
  __shared__ int s_c[MP_];
  const int tid = threadIdx.x, g = blockIdx.x;
  const int lane = tid & 63, wv = tid >> 6;
  if (tid < MP_) s_c[tid] = concepts[g * MP_ + tid];
  for (int idx = tid; idx < S_ * 320; idx += 512) {
    const int j = idx / 320, k = idx % 320;
    s_W1[j][k] = (h16)W1[j * 320 + k];
  }
  __syncthreads();
  {
    const float4* r4 = (const float4*)r;
#pragma unroll
    for (int i = 0; i < 8; ++i) {
      const int idx = tid + i * 512, p = idx >> 6, c4 = idx & 63;
      *(float4*)&s_f[p][c4 * 4] = r4[(size_t)(g * MP_ + p) * 64 + c4];
    }
    const float4* ce4 = (const float4*)cemb;
    const float4 z = make_float4(0.f, 0.f, 0.f, 0.f);
#pragma unroll
    for (int i = 0; i < 2; ++i) {
      const int idx = tid + i * 512, p = idx >> 4, k4 = idx & 15;
      const int c = s_c[p];
      *(float4*)&s_f[p][DV_ + k4 * 4] = c ? ce4[c * 16 + k4] : z;
    }
  }
  __syncthreads();
  const int j = lane;  // neuron
  float acc[8];
  {
    const float b1j = b1[j];
#pragma unroll
    for (int p = 0; p < 8; ++p) acc[p] = b1j;
  }
  for (int k4 = 0; k4 < 80; ++k4) {
    const float4 w4 = h2f(*(const half4*)&s_W1[j][k4 * 4]);
#pragma unroll
    for (int p = 0; p < 8; ++p)
      acc[p] += dot4(w4, *(const float4*)&s_f[wv * 8 + p][k4 * 4]);
  }
#pragma unroll
  for (int p = 0; p < 8; ++p) s_h1[wv][p][j] = fmaxf(acc[p], 0.f);
  __syncthreads();
  {
    const float b2j = b2[j];
#pragma unroll
    for (int p = 0; p < 8; ++p) acc[p] = b2j;
  }
  const float4* w2r = (const float4*)(W2 + j * S_);
#pragma unroll
  for (int k4 = 0; k4 < S_ / 4; ++k4) {
    const float4 w4 = w2r[k4];
#pragma unroll
    for (int p = 0; p < 8; ++p)
      acc[p] += dot4(w4, *(const float4*)&s_h1[wv][p][k4 * 4]);
  }
  const float w3j = W3[j], b3v = b3[0];
#pragma unroll
  for (int p = 0; p < 8; ++p) {
    float pp = fmaxf(acc[p], 0.f) * w3j;
    for (int off = 32; off; off >>= 1) pp += __shfl_xor(pp, off, 64);
    if (lane == 0)
      out[g * MP_ + wv * 8 + p] = 1.f / (1.f + expf(-(pp + b3v)));
  }
}

extern "C" void kernel_launch(void* const* d_in, const int* in_sizes, int n_in,
                              void* d_out, int out_size, void* d_ws, size_t ws_size,
                              hipStream_t stream) {
  const int* concepts = (const int*)d_in[0];
  const int* interactions = (const int*)d_in[1];
  const float* Kmem = (const float*)d_in[2];
  const float* Vmem = (const float*)d_in[3];
  const float* cemb = (const float*)d_in[4];
  const float* iemb = (const float*)d_in[5];
  const float* We = (const float*)d_in[6];
  const float* be = (const float*)d_in[7];
  const float* Wa = (const float*)d_in[8];
  const float* ba = (const float*)d_in[9];
  const float* W1 = (const float*)d_in[10];
  const float* b1 = (const float*)d_in[11];
  const float* W2 = (const float*)d_in[12];
  const float* b2 = (const float*)d_in[13];
  const float* W3 = (const float*)d_in[14];
  const float* b3 = (const float*)d_in[15];
  float* out = (float*)d_out;

  const size_t sz_w = (size_t)NCID * N_ * 4;    // 1.05 MB
  const size_t sz_e = (size_t)NIID * DV_ * 4;   // 1.05 MB
  const size_t sz_r = (size_t)NP_ * DV_ * 4;    // 128 MiB
  float* wtab = (float*)d_ws;
  float* etab = (float*)((char*)d_ws + sz_w);
  float* atab = (float*)((char*)d_ws + sz_w + sz_e);
  float* r    = (float*)((char*)d_ws + sz_w + 2 * sz_e);

  kW<<<dim3(NCID), dim3(512), 0, stream>>>(Kmem, cemb, wtab);
  kG<<<dim3((NIID + 7) / 8), dim3(512), 0, stream>>>(iemb, We, be, Wa, ba, etab, atab);
  hipMemsetAsync(r, 0, sz_r, stream);
  kS<<<dim3(B_ * 4), dim3(512), 0, stream>>>(concepts, interactions, Vmem,
                                             wtab, etab, atab, r);
  kM<<<dim3(NP_ / MP_), dim3(512), 0, stream>>>(concepts, cemb, r,
                                                W1, b1, W2, b2, W3, b3, out);
}

// Round 9
// 6360.481 us; speedup vs baseline: 1.9579x; 1.0062x over previous
//
#include <hip/hip_runtime.h>

// DKVMN forward, round 9 — table-driven pipeline, atomic-free r reduction.
// R8 diagnosis: kS spent ~80% of 5.85 ms on 134M device-scope fp32 atomicAdds
// (WRITE_SIZE 2.1 GB = 134M x 16B RMW), 4 chunk-blocks on different XCDs
// ping-ponging the same r lines. R9: 2 chunks of 256 rows (1024-thr blocks,
// 16 waves x 16 rows x float4 of M in registers for all 512 steps); each block
// writes its partial r NON-atomically as fp16 to its own 64 MiB region; kM
// sums the two partials. No global atomics, no memset.
// Tables: wtab[513][512], etab/atab[1025][256] fp32 (3.1 MiB, L2-hot).
// ws = 3.1 + 128 MiB ~ 131 MiB (< proven 256 MiB capacity).

#define B_ 256
#define T_ 512
#define N_ 512
#define DK_ 64
#define DV_ 256
#define S_ 64
#define NP_ (B_ * T_)
#define NCID 513
#define NIID 1025
#define TB_ 16

typedef _Float16 h16;
typedef __attribute__((ext_vector_type(4))) _Float16 half4;

__device__ __forceinline__ float dot4(float4 a, float4 b) {
  return a.x * b.x + a.y * b.y + a.z * b.z + a.w * b.w;
}
__device__ __forceinline__ float4 h2f(half4 h) {
  return make_float4((float)h.x, (float)h.y, (float)h.z, (float)h.w);
}
__device__ __forceinline__ half4 f2h(float4 f) {
  half4 h;
  h.x = (h16)f.x; h.y = (h16)f.y; h.z = (h16)f.z; h.w = (h16)f.w;
  return h;
}

// ============ kW: wtab[c][n] = softmax_n(q_c . K_n), 513 blocks ============
__global__ __launch_bounds__(512) void kW(const float* __restrict__ Kmem,
                                          const float* __restrict__ cemb,
                                          float* __restrict__ wtab) {
  __shared__ float s_q[DK_];
  __shared__ float s_red[16];
  const int tid = threadIdx.x, c = blockIdx.x;
  if (tid < DK_) s_q[tid] = c ? cemb[c * DK_ + tid] : 0.f;
  __syncthreads();
  const int n = tid;  // 512 threads = N
  const float4* kr = (const float4*)(Kmem + n * DK_);
  float acc = 0.f;
#pragma unroll
  for (int kk = 0; kk < DK_ / 4; ++kk) acc += dot4(kr[kk], *(const float4*)&s_q[kk * 4]);
  const int lane = tid & 63, wid = tid >> 6;
  float mx = acc;
  for (int off = 32; off; off >>= 1) mx = fmaxf(mx, __shfl_xor(mx, off, 64));
  if (lane == 0) s_red[wid] = mx;
  __syncthreads();
  float gmx = s_red[0];
#pragma unroll
  for (int i = 1; i < 8; ++i) gmx = fmaxf(gmx, s_red[i]);
  const float e = expf(acc - gmx);
  float sum = e;
  for (int off = 32; off; off >>= 1) sum += __shfl_xor(sum, off, 64);
  if (lane == 0) s_red[8 + wid] = sum;
  __syncthreads();
  float gs = 0.f;
#pragma unroll
  for (int i = 0; i < 8; ++i) gs += s_red[8 + i];
  wtab[c * N_ + n] = e / gs;
}

// ============ kG: etab/atab[id][d], 129 blocks x 8 ids =====================
__global__ __launch_bounds__(512) void kG(const float* __restrict__ iemb,
                                          const float* __restrict__ We,
                                          const float* __restrict__ be,
                                          const float* __restrict__ Wa,
                                          const float* __restrict__ ba,
                                          float* __restrict__ etab,
                                          float* __restrict__ atab) {
  __shared__ float s_v[8 * DV_];  // 8 KB
  const int tid = threadIdx.x, bi = blockIdx.x;
  {
    const int j = tid >> 6, c4 = tid & 63;
    const int id = bi * 8 + j;
    float4 v = make_float4(0.f, 0.f, 0.f, 0.f);
    if (id >= 1 && id < NIID) v = ((const float4*)iemb)[(size_t)id * 64 + c4];
    *(float4*)&s_v[j * DV_ + c4 * 4] = v;
  }
  __syncthreads();
  const int gate = tid >> 8, d = tid & 255;  // gate wave-uniform
  const float4* wr = (const float4*)((gate ? Wa : We) + d * DV_);
  float acc[8];
#pragma unroll
  for (int j = 0; j < 8; ++j) acc[j] = 0.f;
  for (int kk = 0; kk < DV_ / 4; ++kk) {
    const float4 w4 = wr[kk];
#pragma unroll
    for (int j = 0; j < 8; ++j) acc[j] += dot4(w4, *(const float4*)&s_v[j * DV_ + kk * 4]);
  }
  const float bias = gate ? ba[d] : be[d];
#pragma unroll
  for (int j = 0; j < 8; ++j) {
    const int id = bi * 8 + j;
    if (id < NIID) {
      if (gate) atab[(size_t)id * DV_ + d] = tanhf(acc[j] + bias);
      else      etab[(size_t)id * DV_ + d] = 1.f / (1.f + expf(-(acc[j] + bias)));
    }
  }
}

// ============ kS: in-register recurrence, 512 blocks x 1024 thr ============
// block = (b, ch): 16 waves x 16 rows x float4(lane) = 256 rows of M in regs.
// Partial r written non-atomically (fp16) to this chunk's own region.
__global__ void __attribute__((amdgpu_flat_work_group_size(1024, 1024),
                               amdgpu_waves_per_eu(4, 4)))
kS(const int* __restrict__ concepts, const int* __restrict__ inter,
   const float* __restrict__ Vmem, const float* __restrict__ wtab,
   const float* __restrict__ etab, const float* __restrict__ atab,
   h16* __restrict__ r0, h16* __restrict__ r1) {
  __shared__ float s_wt[TB_][256];    // 16 KB  w for this chunk's 256 rows
  __shared__ float s_e[TB_][DV_];     // 16 KB
  __shared__ float s_a[TB_][DV_];     // 16 KB
  __shared__ float s_rt[TB_][4][64];  // 16 KB  r partials, component planes
  const int tid = threadIdx.x, bx = blockIdx.x;
  const int b = bx >> 1, ch = bx & 1;
  const int lane = tid & 63, wv = tid >> 6;  // 16 waves x 16 rows = 256 rows
  float4 m[16];                              // 64 VGPRs of true state
  {
    const float4* vm4 = (const float4*)Vmem;
    const int nb = ch * 256 + wv * 16;
#pragma unroll
    for (int rr = 0; rr < 16; ++rr) m[rr] = vm4[(nb + rr) * 64 + lane];
  }
  const int* cb = concepts + b * T_;
  const int* ib = inter + b * T_;
  h16* rb = (ch ? r1 : r0) + (size_t)b * T_ * DV_;
  const float4* wtab4 = (const float4*)wtab;
  const float4* etab4 = (const float4*)etab;
  const float4* atab4 = (const float4*)atab;

  for (int t0 = 0; t0 < T_; t0 += TB_) {
    // ---- stage w/e/a tiles from hot tables; zero r planes ----
    {
      const int tl = tid >> 6, q = tid & 63;  // 1024 = 16 x 64 float4
      const int c = cb[t0 + tl];
      ((float4*)s_wt)[tid] = wtab4[(size_t)c * 128 + ch * 64 + q];
      const int iv = ib[t0 + tl];
      *(float4*)&s_e[tl][q * 4] = etab4[(size_t)iv * 64 + q];
      *(float4*)&s_a[tl][q * 4] = atab4[(size_t)iv * 64 + q];
      ((float4*)s_rt)[tid] = make_float4(0.f, 0.f, 0.f, 0.f);
    }
    __syncthreads();

    // ---- 16 timesteps over register-resident state ----
    for (int tl = 0; tl < TB_; ++tl) {
      float wr_[16];
      *(float4*)&wr_[0]  = *(const float4*)&s_wt[tl][wv * 16 + 0];
      *(float4*)&wr_[4]  = *(const float4*)&s_wt[tl][wv * 16 + 4];
      *(float4*)&wr_[8]  = *(const float4*)&s_wt[tl][wv * 16 + 8];
      *(float4*)&wr_[12] = *(const float4*)&s_wt[tl][wv * 16 + 12];
      const float4 e4 = *(const float4*)&s_e[tl][lane * 4];
      const float4 a4 = *(const float4*)&s_a[tl][lane * 4];
      float4 racc = make_float4(0.f, 0.f, 0.f, 0.f);
#pragma unroll
      for (int rr = 0; rr < 16; ++rr) {
        const float w = wr_[rr];
        racc.x = fmaf(w, m[rr].x, racc.x);
        racc.y = fmaf(w, m[rr].y, racc.y);
        racc.z = fmaf(w, m[rr].z, racc.z);
        racc.w = fmaf(w, m[rr].w, racc.w);
        m[rr].x = fmaf(-w, fmaf(e4.x, m[rr].x, -a4.x), m[rr].x);
        m[rr].y = fmaf(-w, fmaf(e4.y, m[rr].y, -a4.y), m[rr].y);
        m[rr].z = fmaf(-w, fmaf(e4.z, m[rr].z, -a4.z), m[rr].z);
        m[rr].w = fmaf(-w, fmaf(e4.w, m[rr].w, -a4.w), m[rr].w);
      }
      atomicAdd(&s_rt[tl][0][lane], racc.x);
      atomicAdd(&s_rt[tl][1][lane], racc.y);
      atomicAdd(&s_rt[tl][2][lane], racc.z);
      atomicAdd(&s_rt[tl][3][lane], racc.w);
    }
    __syncthreads();

    // ---- drain partial r (fp16, non-atomic, coalesced 8B/thread) ----
    {
      const int tl = tid >> 6, l = tid & 63;
      const float4 v = make_float4(s_rt[tl][0][l], s_rt[tl][1][l],
                                   s_rt[tl][2][l], s_rt[tl][3][l]);
      *(half4*)(rb + (size_t)(t0 + tl) * DV_ + l * 4) = f2h(v);
    }
    __syncthreads();  // s_rt reads done before next tile zeroes it
  }
}

// ============ kM: MLP head, 2048 blocks x 512 thr ==========================
#define MP_ 64
__global__ __launch_bounds__(512) void kM(const int* __restrict__ concepts,
                                          const float* __restrict__ cemb,
                                          const h16* __restrict__ r0,
                                          const h16* __restrict__ r1,
                                          const float* __restrict__ W1,
                                          const float* __restrict__ b1,
                                          const float* __restrict__ W2,
                                          const float* __restrict__ b2,
                                          const float* __restrict__ W3,
                                          const float* __restrict__ b3,
                                          float* __restrict__ out) {
  __shared__ float s_f[MP_][DV_ + DK_];  // 80 KB
  __shared__ h16 s_W1[S_][324];          // 40.5 KB (padded)
  __shared__ float s_h1[8][8][S_];       // 16 KB
  __shared__ int s_c[MP_];
  const int tid = threadIdx.x, g = blockIdx.x;
  const int lane = tid & 63, wv = tid >> 6;
  if (tid < MP_) s_c[tid] = concepts[g * MP_ + tid];
  for (int idx = tid; idx < S_ * 320; idx += 512) {
    const int j = idx / 320, k = idx % 320;
    s_W1[j][k] = (h16)W1[j * 320 + k];
  }
  __syncthreads();
  {
    const half4* r04 = (const half4*)r0;
    const half4* r14 = (const half4*)r1;
#pragma unroll
    for (int i = 0; i < 8; ++i) {
      const int idx = tid + i * 512, p = idx >> 6, c4 = idx & 63;
      const float4 v0 = h2f(r04[(size_t)(g * MP_ + p) * 64 + c4]);
      const float4 v1 = h2f(r14[(size_t)(g * MP_ + p) * 64 + c4]);
      *(float4*)&s_f[p][c4 * 4] =
          make_float4(v0.x + v1.x, v0.y + v1.y, v0.z + v1.z, v0.w + v1.w);
    }
    const float4* ce4 = (const float4*)cemb;
    const float4 z = make_float4(0.f, 0.f, 0.f, 0.f);
#pragma unroll
    for (int i = 0; i < 2; ++i) {
      const int idx = tid + i * 512, p = idx >> 4, k4 = idx & 15;
      const int c = s_c[p];
      *(float4*)&s_f[p][DV_ + k4 * 4] = c ? ce4[c * 16 + k4] : z;
    }
  }
  __syncthreads();
  const int j = lane;  // neuron
  float acc[8];
  {
    const float b1j = b1[j];
#pragma unroll
    for (int p = 0; p < 8; ++p) acc[p] = b1j;
  }
  for (int k4 = 0; k4 < 80; ++k4) {
    const float4 w4 = h2f(*(const half4*)&s_W1[j][k4 * 4]);
#pragma unroll
    for (int p = 0; p < 8; ++p)
      acc[p] += dot4(w4, *(const float4*)&s_f[wv * 8 + p][k4 * 4]);
  }
#pragma unroll
  for (int p = 0; p < 8; ++p) s_h1[wv][p][j] = fmaxf(acc[p], 0.f);
  __syncthreads();
  {
    const float b2j = b2[j];
#pragma unroll
    for (int p = 0; p < 8; ++p) acc[p] = b2j;
  }
  const float4* w2r = (const float4*)(W2 + j * S_);
#pragma unroll
  for (int k4 = 0; k4 < S_ / 4; ++k4) {
    const float4 w4 = w2r[k4];
#pragma unroll
    for (int p = 0; p < 8; ++p)
      acc[p] += dot4(w4, *(const float4*)&s_h1[wv][p][k4 * 4]);
  }
  const float w3j = W3[j], b3v = b3[0];
#pragma unroll
  for (int p = 0; p < 8; ++p) {
    float pp = fmaxf(acc[p], 0.f) * w3j;
    for (int off = 32; off; off >>= 1) pp += __shfl_xor(pp, off, 64);
    if (lane == 0)
      out[g * MP_ + wv * 8 + p] = 1.f / (1.f + expf(-(pp + b3v)));
  }
}

extern "C" void kernel_launch(void* const* d_in, const int* in_sizes, int n_in,
                              void* d_out, int out_size, void* d_ws, size_t ws_size,
                              hipStream_t stream) {
  const int* concepts = (const int*)d_in[0];
  const int* interactions = (const int*)d_in[1];
  const float* Kmem = (const float*)d_in[2];
  const float* Vmem = (const float*)d_in[3];
  const float* cemb = (const float*)d_in[4];
  const float* iemb = (const float*)d_in[5];
  const float* We = (const float*)d_in[6];
  const float* be = (const float*)d_in[7];
  const float* Wa = (const float*)d_in[8];
  const float* ba = (const float*)d_in[9];
  const float* W1 = (const float*)d_in[10];
  const float* b1 = (const float*)d_in[11];
  const float* W2 = (const float*)d_in[12];
  const float* b2 = (const float*)d_in[13];
  const float* W3 = (const float*)d_in[14];
  const float* b3 = (const float*)d_in[15];
  float* out = (float*)d_out;

  const size_t sz_w = (size_t)NCID * N_ * 4;    // 1.05 MB
  const size_t sz_e = (size_t)NIID * DV_ * 4;   // 1.05 MB
  const size_t sz_rp = (size_t)NP_ * DV_ * 2;   // 64 MiB per chunk partial
  float* wtab = (float*)d_ws;
  float* etab = (float*)((char*)d_ws + sz_w);
  float* atab = (float*)((char*)d_ws + sz_w + sz_e);
  h16* r0 = (h16*)((char*)d_ws + sz_w + 2 * sz_e);
  h16* r1 = (h16*)((char*)d_ws + sz_w + 2 * sz_e + sz_rp);

  kW<<<dim3(NCID), dim3(512), 0, stream>>>(Kmem, cemb, wtab);
  kG<<<dim3((NIID + 7) / 8), dim3(512), 0, stream>>>(iemb, We, be, Wa, ba, etab, atab);
  kS<<<dim3(B_ * 2), dim3(1024), 0, stream>>>(concepts, interactions, Vmem,
                                              wtab, etab, atab, r0, r1);
  kM<<<dim3(NP_ / MP_), dim3(512), 0, stream>>>(concepts, cemb, r0, r1,
                                                W1, b1, W2, b2, W3, b3, out);
}